// Round 17
// baseline (733.567 us; speedup 1.0000x reference)
//
#include <hip/hip_runtime.h>
#include <math.h>

#define BSZ 16
#define LQ 1024
#define DM 256
#define DI 512
#define NT (BSZ*LQ)   // 16384 tokens

typedef __attribute__((ext_vector_type(8))) short short8;
typedef __attribute__((ext_vector_type(4))) short short4v;
typedef __attribute__((ext_vector_type(4))) float f32x4;

#define AS1(p) (const __attribute__((address_space(1))) void*)(p)
#define AS3(p) (__attribute__((address_space(3))) void*)(p)
#define GLOAD16(g, l) __builtin_amdgcn_global_load_lds(AS1(g), AS3(l), 16, 0, 0)

__device__ __forceinline__ short f2bf(float f) {
  union { float f; unsigned u; } a; a.f = f;
  unsigned r = (a.u + 0x7FFF + ((a.u >> 16) & 1)) >> 16;
  return (short)r;
}
__device__ __forceinline__ float bf2f(short s) {
  union { unsigned u; float f; } a; a.u = ((unsigned)(unsigned short)s) << 16;
  return a.f;
}

// ---------------- stem: conv1d(k=3,pad=1) + bias + relu, output (B,L,DM) fp32 ----------------
__global__ void stem_kernel(const float* __restrict__ x, const float* __restrict__ w,
                            const float* __restrict__ bias, float* __restrict__ h) {
  int idx = blockIdx.x * 256 + threadIdx.x;   // over NT*DM = 4M
  int d = idx & 255;
  int l = (idx >> 8) & 1023;
  int b = idx >> 18;
  float acc = bias[d];
#pragma unroll
  for (int c = 0; c < 3; c++) {
    const float* xr = x + (size_t)(b * 3 + c) * LQ;
    const float* wr = w + (size_t)(d * 3 + c) * 3;
#pragma unroll
    for (int k = 0; k < 3; k++) {
      int t = l + k - 1;
      if (t >= 0 && t < LQ) acc += xr[t] * wr[k];
    }
  }
  h[idx] = fmaxf(acc, 0.f);
}

// ---------------- weight conversion fp32 -> bf16 (x_proj padded to 64 rows) ----------------
#define WB_IN 262144          // 1024*256
#define WB_XP 32768           // 64*512 (rows >=48 zero)
#define WB_OUT 131072         // 256*512
#define WB_L (WB_IN + WB_XP + WB_OUT)

__global__ void convert_w(const float* __restrict__ in_w, const float* __restrict__ xp_w,
                          const float* __restrict__ out_w, short* __restrict__ wb) {
  int layer = blockIdx.y;
  int idx = blockIdx.x * 256 + threadIdx.x;
  short* dst = wb + (size_t)layer * WB_L;
  float v;
  if (idx < WB_IN) {
    v = in_w[(size_t)layer * WB_IN + idx];
  } else if (idx < WB_IN + WB_XP) {
    int k = idx - WB_IN; int row = k >> 9, col = k & 511;
    v = (row < 48) ? xp_w[(size_t)layer * 48 * 512 + row * 512 + col] : 0.f;
  } else {
    int k = idx - WB_IN - WB_XP;
    v = out_w[(size_t)layer * WB_OUT + k];
  }
  dst[idx] = f2bf(v);
}

// ---------------- layernorm over DM=256 -> bf16 out; one WAVE per token ----------------
__global__ void ln_kernel(const float* __restrict__ x, const float* __restrict__ g,
                          const float* __restrict__ bv, short* __restrict__ o) {
  int token = blockIdx.x * 4 + (threadIdx.x >> 6);
  int lane = threadIdx.x & 63;
  f32x4 v = *(const f32x4*)(x + (size_t)token * DM + lane * 4);
  float s = v[0] + v[1] + v[2] + v[3];
  float q = v[0]*v[0] + v[1]*v[1] + v[2]*v[2] + v[3]*v[3];
#pragma unroll
  for (int off = 32; off > 0; off >>= 1) {
    s += __shfl_xor(s, off, 64);
    q += __shfl_xor(q, off, 64);
  }
  float mu = s * (1.f / DM);
  float var = q * (1.f / DM) - mu * mu;
  float rs = rsqrtf(var + 1e-5f);
  f32x4 gg = *(const f32x4*)(g + lane * 4);
  f32x4 bb = *(const f32x4*)(bv + lane * 4);
  short4v ov;
#pragma unroll
  for (int k = 0; k < 4; k++) ov[k] = f2bf((v[k] - mu) * rs * gg[k] + bb[k]);
  *(short4v*)(o + (size_t)token * DM + lane * 4) = ov;
}

// ---------------- bf16 MFMA GEMM, 128x128 tile, BK=64 via two stacked 128x32 LDS blocks ----------------
// bf16 split store (for in_proj). K=256 -> 4 iters, 8 barriers.
__global__ __launch_bounds__(256) void gemm_mfma_s16(
    const short* __restrict__ A, int K,
    const short* __restrict__ W,
    short* __restrict__ C0, int ld0,
    short* __restrict__ C1, int ld1,
    int split, int N) {
  __shared__ short As[2][128 * 32];
  __shared__ short Bs[2][128 * 32];
  int tid = threadIdx.x;
  int wave = tid >> 6, lane = tid & 63;
  int bm = blockIdx.y * 128, bn = blockIdx.x * 128;
  int wm = (wave >> 1) * 64, wn = (wave & 1) * 64;

  f32x4 acc[4][4];
#pragma unroll
  for (int i = 0; i < 4; i++)
#pragma unroll
    for (int j = 0; j < 4; j++) { acc[i][j][0]=0.f; acc[i][j][1]=0.f; acc[i][j][2]=0.f; acc[i][j][3]=0.f; }

  int srow = lane >> 2;          // 16 rows per GLOAD16
  int scol = (lane & 3) * 8;     // 4 x 16B chunks per row of 32 shorts
  const short* Ag = A + (size_t)(bm + wave * 32 + srow) * K + scol;
  const short* Wg = W + (size_t)(bn + wave * 32 + srow) * K + scol;
  short* As0W = As[0] + wave * 32 * 32;
  short* As1W = As[1] + wave * 32 * 32;
  short* Bs0W = Bs[0] + wave * 32 * 32;
  short* Bs1W = Bs[1] + wave * 32 * 32;

  int fr = lane & 15;
  int kg = (lane >> 4) * 8;

  for (int k0 = 0; k0 < K; k0 += 64) {
    GLOAD16(Ag + k0,                         As0W);
    GLOAD16(Ag + k0 + (size_t)16 * K,        As0W + 16 * 32);
    GLOAD16(Ag + k0 + 32,                    As1W);
    GLOAD16(Ag + k0 + 32 + (size_t)16 * K,   As1W + 16 * 32);
    GLOAD16(Wg + k0,                         Bs0W);
    GLOAD16(Wg + k0 + (size_t)16 * K,        Bs0W + 16 * 32);
    GLOAD16(Wg + k0 + 32,                    Bs1W);
    GLOAD16(Wg + k0 + 32 + (size_t)16 * K,   Bs1W + 16 * 32);
    __syncthreads();

#pragma unroll
    for (int ks = 0; ks < 2; ks++) {
      short8 af[4], bf[4];
#pragma unroll
      for (int i = 0; i < 4; i++) af[i] = *(const short8*)&As[ks][(wm + i * 16 + fr) * 32 + kg];
#pragma unroll
      for (int j = 0; j < 4; j++) bf[j] = *(const short8*)&Bs[ks][(wn + j * 16 + fr) * 32 + kg];
#pragma unroll
      for (int i = 0; i < 4; i++)
#pragma unroll
        for (int j = 0; j < 4; j++)
          acc[i][j] = __builtin_amdgcn_mfma_f32_16x16x32_bf16(af[i], bf[j], acc[i][j], 0, 0, 0);
    }
    __syncthreads();
  }

  int cn = lane & 15, cr = (lane >> 4) * 4;
#pragma unroll
  for (int i = 0; i < 4; i++) {
    int row0 = bm + wm + i * 16 + cr;
#pragma unroll
    for (int j = 0; j < 4; j++) {
      int col = bn + wn + j * 16 + cn;
      if (col < N) {
#pragma unroll
        for (int r = 0; r < 4; r++) {
          short* p = (col < split) ? (C0 + (size_t)(row0 + r) * ld0 + col)
                                   : (C1 + (size_t)(row0 + r) * ld1 + (col - split));
          *p = f2bf(acc[i][j][r]);
        }
      }
    }
  }
}

// ---------------- fused conv+silu + x_proj GEMM; writes xinb as byproduct ----------------
// 32-token tiles, grid (1, NT/32) = 512 blocks (2/CU). Conv for the A-tile is computed
// inline between the W-tile global_load_lds issue and the barrier (hidden under DMA).
__global__ __launch_bounds__(256) void gemm2_conv(
    const short* __restrict__ xcb, const float* __restrict__ cw, const float* __restrict__ cb,
    const short* __restrict__ W, short* __restrict__ xinb, float* __restrict__ proj) {
  __shared__ short As[32 * 72];    // stride 72 shorts = 144B (16B-aligned rows)
  __shared__ short Bs[64 * 64];
  __shared__ float sCW[512 * 4];
  __shared__ float sCB[512];
  int tid = threadIdx.x;
  int wave = tid >> 6, lane = tid & 63;
  int bm = blockIdx.y * 32;
  int wm = (wave >> 1) * 16, wn = (wave & 1) * 32;

  for (int i = tid; i < 2048; i += 256) sCW[i] = cw[i];
  for (int i = tid; i < 512; i += 256) sCB[i] = cb[i];
  __syncthreads();

  f32x4 acc[2];
  acc[0] = (f32x4){0.f,0.f,0.f,0.f};
  acc[1] = (f32x4){0.f,0.f,0.f,0.f};

  int fr = lane & 15, kg = (lane >> 4) * 8;
  int r = tid >> 3;              // token row 0..31
  int cg = (tid & 7) * 8;        // channel group within 64
  int t = bm + r;
  int l = t & 1023;

  for (int k0 = 0; k0 < 512; k0 += 64) {
    // stage W tile (async DMA)
#pragma unroll
    for (int i = 0; i < 2; i++) {
      int c = tid + i * 256;
      GLOAD16(W + (size_t)(c >> 3) * 512 + k0 + (c & 7) * 8, Bs + c * 8);
    }
    // conv + silu for 8 channels of this token (overlaps the DMA)
    int ch0 = k0 + cg;
    short8 xv[4];
#pragma unroll
    for (int k = 0; k < 4; k++) {
      if (l + k - 3 >= 0) xv[k] = *(const short8*)(xcb + (size_t)(t + k - 3) * 512 + ch0);
      else xv[k] = (short8)0;
    }
    short8 ov;
#pragma unroll
    for (int e = 0; e < 8; e++) {
      f32x4 wv = *(const f32x4*)&sCW[(ch0 + e) * 4];
      float a = sCB[ch0 + e];
#pragma unroll
      for (int k = 0; k < 4; k++) a += bf2f(xv[k][e]) * wv[k];
      a = a / (1.f + __expf(-a));
      ov[e] = f2bf(a);
    }
    *(short8*)&As[r * 72 + cg] = ov;
    *(short8*)(xinb + (size_t)t * 512 + ch0) = ov;
    __syncthreads();

#pragma unroll
    for (int ks = 0; ks < 2; ks++) {
      short8 af = *(const short8*)&As[(wm + fr) * 72 + ks * 32 + kg];
#pragma unroll
      for (int j = 0; j < 2; j++) {
        short8 bf = *(const short8*)&Bs[(wn + j * 16 + fr) * 64 + ks * 32 + kg];
        acc[j] = __builtin_amdgcn_mfma_f32_16x16x32_bf16(af, bf, acc[j], 0, 0, 0);
      }
    }
    __syncthreads();
  }

  int cn = lane & 15, cr = (lane >> 4) * 4;
  int row0 = bm + wm + cr;
#pragma unroll
  for (int j = 0; j < 2; j++) {
    int col = wn + j * 16 + cn;
    if (col < 48) {
#pragma unroll
      for (int rr2 = 0; rr2 < 4; rr2++)
        proj[(size_t)(row0 + rr2) * 48 + col] = acc[j][rr2];
    }
  }
}

// ---------------- bf16 MFMA GEMM, 64x64 tile BK=64 (out_proj), fp32 C accum ----------------
__global__ __launch_bounds__(256) void gemm_mfma64(
    const short* __restrict__ A, int K,
    const short* __restrict__ W,
    float* __restrict__ C, int ldc, int N, int accum) {
  __shared__ short As[64 * 64];
  __shared__ short Bs[64 * 64];
  int tid = threadIdx.x;
  int wave = tid >> 6, lane = tid & 63;
  int bm = blockIdx.y * 64, bn = blockIdx.x * 64;
  int wm = (wave >> 1) * 32, wn = (wave & 1) * 32;

  f32x4 acc[2][2];
#pragma unroll
  for (int i = 0; i < 2; i++)
#pragma unroll
    for (int j = 0; j < 2; j++) { acc[i][j][0]=0.f; acc[i][j][1]=0.f; acc[i][j][2]=0.f; acc[i][j][3]=0.f; }

  const short* Ag = A + (size_t)bm * K;
  const short* Wg = W + (size_t)bn * K;
  int fr = lane & 15;
  int kg = (lane >> 4) * 8;

  for (int k0 = 0; k0 < K; k0 += 64) {
#pragma unroll
    for (int i = 0; i < 2; i++) {
      int c = tid + i * 256;
      int row = c >> 3, kk = (c & 7) * 8;
      GLOAD16(Ag + (size_t)row * K + k0 + kk, As + c * 8);
      GLOAD16(Wg + (size_t)row * K + k0 + kk, Bs + c * 8);
    }
    __syncthreads();

#pragma unroll
    for (int ks = 0; ks < 2; ks++) {
      short8 af[2], bf[2];
#pragma unroll
      for (int i = 0; i < 2; i++) af[i] = *(const short8*)&As[(wm + i * 16 + fr) * 64 + ks * 32 + kg];
#pragma unroll
      for (int j = 0; j < 2; j++) bf[j] = *(const short8*)&Bs[(wn + j * 16 + fr) * 64 + ks * 32 + kg];
#pragma unroll
      for (int i = 0; i < 2; i++)
#pragma unroll
        for (int j = 0; j < 2; j++)
          acc[i][j] = __builtin_amdgcn_mfma_f32_16x16x32_bf16(af[i], bf[j], acc[i][j], 0, 0, 0);
    }
    __syncthreads();
  }

  int cn = lane & 15, cr = (lane >> 4) * 4;
#pragma unroll
  for (int i = 0; i < 2; i++) {
    int row0 = bm + wm + i * 16 + cr;
#pragma unroll
    for (int j = 0; j < 2; j++) {
      int col = bn + wn + j * 16 + cn;
      if (col < N) {
#pragma unroll
        for (int r = 0; r < 4; r++) {
          float v = acc[i][j][r];
          float* p = C + (size_t)(row0 + r) * ldc + col;
          if (accum) v += *p;
          *p = v;
        }
      }
    }
  }
}

// ---------------- 16-lane sum via DPP ----------------
template <int CTRL>
__device__ __forceinline__ float dpp_add(float x) {
  int yi = __builtin_amdgcn_update_dpp(0, __float_as_int(x), CTRL, 0xF, 0xF, true);
  return x + __int_as_float(yi);
}
__device__ __forceinline__ float sum16(float x) {
  x = dpp_add<0xB1>(x);   // quad_perm xor1
  x = dpp_add<0x4E>(x);   // quad_perm xor2
  x = dpp_add<0x124>(x);  // row_ror:4
  x = dpp_add<0x128>(x);  // row_ror:8
  return x;
}

// ---------------- fused delta-proj + selective scan + Dp skip + silu(z) gate ----------------
// TCH=32, 3x __syncthreads per chunk (R12-proven; wave_barrier B1 variant regressed in R16).
#define TCH 32
__global__ __launch_bounds__(256) void scan_kernel(
    const short* __restrict__ xinb, const float* __restrict__ proj,
    const short* __restrict__ zc,
    const float* __restrict__ dt_w, const float* __restrict__ dt_b,
    const float* __restrict__ A_log, const float* __restrict__ Dp,
    short* __restrict__ ybf) {
  int b  = blockIdx.x >> 5;
  int d0 = (blockIdx.x & 31) << 4;
  int tid = threadIdx.x;
  int ci = tid >> 4;
  int s  = tid & 15;
  int d = d0 + ci;

  __shared__ float sDt[32 * 20];
  __shared__ float sBT[16 * 36];
  __shared__ float sCT[16 * 36];
  __shared__ float sUT[16 * 36];
  __shared__ float sDU[16 * 36];
  __shared__ float sDel[16 * 36];
  __shared__ float sY[32 * 17];

  float Av = -__expf(A_log[(size_t)d * 16 + s]);
  f32x4 wv4[4];
#pragma unroll
  for (int k = 0; k < 4; k++) wv4[k] = *(const f32x4*)&dt_w[(size_t)d * 16 + k * 4];
  float db = dt_b[d];
  float Ddj = Dp[d0 + s];
  float h = 0.f;

  const float* projb = proj + (size_t)b * LQ * 48;
  const short* xinbb = xinb + (size_t)b * LQ * 512 + d0;
  const short* zcb   = zc   + (size_t)b * LQ * 512 + d0;
  short* ybb         = ybf  + (size_t)b * LQ * 512 + d0;

  int tt = tid >> 4, j = tid & 15;

  int tr[6], rr[6];
#pragma unroll
  for (int k = 0; k < 6; k++) { int idx = tid + k * 256; tr[k] = idx / 48; rr[k] = idx - tr[k] * 48; }

  float uv0, uv1, zv0, zv1;
  {
    float pjv[6];
#pragma unroll
    for (int k = 0; k < 6; k++) pjv[k] = projb[tid + k * 256];
    uv0 = bf2f(xinbb[(size_t)tt * 512 + j]);
    uv1 = bf2f(xinbb[(size_t)(tt + 16) * 512 + j]);
    zv0 = bf2f(zcb[(size_t)tt * 512 + j]);
    zv1 = bf2f(zcb[(size_t)(tt + 16) * 512 + j]);
#pragma unroll
    for (int k = 0; k < 6; k++) {
      int r = rr[k], t = tr[k];
      if (r < 16)      sDt[t * 20 + r] = pjv[k];
      else if (r < 32) sBT[(r - 16) * 36 + t] = pjv[k];
      else             sCT[(r - 32) * 36 + t] = pjv[k];
    }
    sUT[j * 36 + tt] = uv0;
    sUT[j * 36 + tt + 16] = uv1;
  }
  __syncthreads();

  const int NCH = LQ / TCH;
  for (int c = 0; c < NCH; c++) {
    int t0 = c * TCH;

    float pjn[6], un0 = 0.f, un1 = 0.f, zn0 = 0.f, zn1 = 0.f;
    if (c + 1 < NCH) {
      const float* g = projb + (t0 + TCH) * 48;
#pragma unroll
      for (int k = 0; k < 6; k++) pjn[k] = g[tid + k * 256];
      un0 = bf2f(xinbb[(size_t)(t0 + TCH + tt) * 512 + j]);
      un1 = bf2f(xinbb[(size_t)(t0 + TCH + tt + 16) * 512 + j]);
      zn0 = bf2f(zcb[(size_t)(t0 + TCH + tt) * 512 + j]);
      zn1 = bf2f(zcb[(size_t)(t0 + TCH + tt + 16) * 512 + j]);
    }

    {
      f32x4 a0 = *(const f32x4*)&sDt[s * 20 + 0];
      f32x4 a1 = *(const f32x4*)&sDt[s * 20 + 4];
      f32x4 a2 = *(const f32x4*)&sDt[s * 20 + 8];
      f32x4 a3 = *(const f32x4*)&sDt[s * 20 + 12];
      f32x4 b0 = *(const f32x4*)&sDt[(s + 16) * 20 + 0];
      f32x4 b1 = *(const f32x4*)&sDt[(s + 16) * 20 + 4];
      f32x4 b2 = *(const f32x4*)&sDt[(s + 16) * 20 + 8];
      f32x4 b3 = *(const f32x4*)&sDt[(s + 16) * 20 + 12];
      float dt0 = db, dt1 = db;
#pragma unroll
      for (int q = 0; q < 4; q++) {
        dt0 += a0[q] * wv4[0][q] + a1[q] * wv4[1][q] + a2[q] * wv4[2][q] + a3[q] * wv4[3][q];
        dt1 += b0[q] * wv4[0][q] + b1[q] * wv4[1][q] + b2[q] * wv4[2][q] + b3[q] * wv4[3][q];
      }
      float de0 = (dt0 > 15.f) ? dt0 : __logf(1.f + __expf(dt0));
      float de1 = (dt1 > 15.f) ? dt1 : __logf(1.f + __expf(dt1));
      float u0 = sUT[ci * 36 + s];
      float u1 = sUT[ci * 36 + s + 16];
      sDel[ci * 36 + s]      = de0;
      sDel[ci * 36 + s + 16] = de1;
      sDU[ci * 36 + s]       = de0 * u0;
      sDU[ci * 36 + s + 16]  = de1 * u1;
    }
    __syncthreads();   // B1

    {
      float ee[TCH], cin[TCH];
      f32x4 ct[8];
      {
        f32x4 dl[8], du8[8], bt[8];
#pragma unroll
        for (int k = 0; k < 8; k++) {
          dl[k]  = *(const f32x4*)&sDel[ci * 36 + k * 4];
          du8[k] = *(const f32x4*)&sDU[ci * 36 + k * 4];
          bt[k]  = *(const f32x4*)&sBT[s * 36 + k * 4];
          ct[k]  = *(const f32x4*)&sCT[s * 36 + k * 4];
        }
#pragma unroll
        for (int t = 0; t < TCH; t++) {
          ee[t] = __expf(dl[t >> 2][t & 3] * Av);
          cin[t] = du8[t >> 2][t & 3] * bt[t >> 2][t & 3];
        }
      }
      float pv0 = 0.f, pv1 = 0.f;
#pragma unroll
      for (int t = 0; t < TCH; t++) {
        h = h * ee[t] + cin[t];
        float p = sum16(h * ct[t >> 2][t & 3]);
        if (t < 16) pv0 = (s == t) ? p : pv0;
        else        pv1 = (s == (t - 16)) ? p : pv1;
      }
      sY[s * 17 + ci] = pv0;
      sY[(s + 16) * 17 + ci] = pv1;
    }
    __syncthreads();   // B2

    {
      float p0 = sY[tt * 17 + j];
      float p1 = sY[(tt + 16) * 17 + j];
      float y0 = p0 + uv0 * Ddj;
      float y1 = p1 + uv1 * Ddj;
      float g0 = zv0 / (1.f + __expf(-zv0));
      float g1 = zv1 / (1.f + __expf(-zv1));
      ybb[(size_t)(t0 + tt) * 512 + j] = f2bf(y0 * g0);
      ybb[(size_t)(t0 + tt + 16) * 512 + j] = f2bf(y1 * g1);
    }
    if (c + 1 < NCH) {
#pragma unroll
      for (int k = 0; k < 6; k++) {
        int r = rr[k], t = tr[k];
        if (r < 16)      sDt[t * 20 + r] = pjn[k];
        else if (r < 32) sBT[(r - 16) * 36 + t] = pjn[k];
        else             sCT[(r - 32) * 36 + t] = pjn[k];
      }
      sUT[j * 36 + tt] = un0;
      sUT[j * 36 + tt + 16] = un1;
      uv0 = un0; uv1 = un1; zv0 = zn0; zv1 = zn1;
    }
    __syncthreads();   // B3
  }
}

// ---------------- final LN + head dot + sigmoid; one WAVE per token ----------------
__global__ void head_kernel(const float* __restrict__ h, const float* __restrict__ g,
                            const float* __restrict__ bv, const float* __restrict__ hw,
                            const float* __restrict__ hb, float* __restrict__ out) {
  int token = blockIdx.x * 4 + (threadIdx.x >> 6);
  int lane = threadIdx.x & 63;
  f32x4 v = *(const f32x4*)(h + (size_t)token * DM + lane * 4);
  float s = v[0] + v[1] + v[2] + v[3];
  float q = v[0]*v[0] + v[1]*v[1] + v[2]*v[2] + v[3]*v[3];
#pragma unroll
  for (int off = 32; off > 0; off >>= 1) {
    s += __shfl_xor(s, off, 64);
    q += __shfl_xor(q, off, 64);
  }
  float mu = s * (1.f / DM);
  float rs = rsqrtf(q * (1.f / DM) - mu * mu + 1e-5f);
  f32x4 gg = *(const f32x4*)(g + lane * 4);
  f32x4 bb = *(const f32x4*)(bv + lane * 4);
  f32x4 ww = *(const f32x4*)(hw + lane * 4);
  float c = 0.f;
#pragma unroll
  for (int k = 0; k < 4; k++) c += ((v[k] - mu) * rs * gg[k] + bb[k]) * ww[k];
#pragma unroll
  for (int off = 32; off > 0; off >>= 1) c += __shfl_xor(c, off, 64);
  if (lane == 0) out[token] = 1.f / (1.f + __expf(-(c + hb[0])));
}

extern "C" void kernel_launch(void* const* d_in, const int* in_sizes, int n_in,
                              void* d_out, int out_size, void* d_ws, size_t ws_size,
                              hipStream_t stream) {
  const float* x        = (const float*)d_in[0];
  const float* stem_w   = (const float*)d_in[1];
  const float* stem_b   = (const float*)d_in[2];
  const float* norm_g   = (const float*)d_in[3];
  const float* norm_b   = (const float*)d_in[4];
  const float* in_proj_w= (const float*)d_in[5];
  const float* conv_w   = (const float*)d_in[6];
  const float* conv_b   = (const float*)d_in[7];
  const float* x_proj_w = (const float*)d_in[8];
  const float* dt_w     = (const float*)d_in[9];
  const float* dt_b     = (const float*)d_in[10];
  const float* A_log    = (const float*)d_in[11];
  const float* Dp       = (const float*)d_in[12];
  const float* out_w    = (const float*)d_in[13];
  const float* fnorm_g  = (const float*)d_in[14];
  const float* fnorm_b  = (const float*)d_in[15];
  const float* head_w   = (const float*)d_in[16];
  const float* head_b   = (const float*)d_in[17];

  char* base = (char*)d_ws;
  float* h    = (float*)(base);                           // 16 MB
  short* xcb  = (short*)(base + ((size_t)16 << 20));      // 16 MB
  short* zcb  = (short*)(base + ((size_t)32 << 20));      // 16 MB
  short* xnb  = (short*)(base + ((size_t)48 << 20));      // 8 MB
  short* xinb = (short*)(base + ((size_t)56 << 20));      // 16 MB
  short* ybf  = (short*)(base + ((size_t)72 << 20));      // 16 MB
  float* proj = (float*)(base + ((size_t)88 << 20));      // 3 MB
  short* wb   = (short*)(base + ((size_t)91 << 20));      // 3.5 MB

  stem_kernel<<<NT, 256, 0, stream>>>(x, stem_w, stem_b, h);

  dim3 gcw(WB_L / 256, 4);
  convert_w<<<gcw, 256, 0, stream>>>(in_proj_w, x_proj_w, out_w, wb);

  for (int i = 0; i < 4; i++) {
    const short* wbl = wb + (size_t)i * WB_L;

    ln_kernel<<<NT / 4, 256, 0, stream>>>(h, norm_g + i * DM, norm_b + i * DM, xnb);

    dim3 g1(8, NT / 128);
    gemm_mfma_s16<<<g1, 256, 0, stream>>>(xnb, 256, wbl, xcb, 512, zcb, 512, 512, 1024);

    dim3 g2(1, NT / 32);
    gemm2_conv<<<g2, 256, 0, stream>>>(xcb, conv_w + i * DI * 4, conv_b + i * DI,
                                       wbl + WB_IN, xinb, proj);

    scan_kernel<<<512, 256, 0, stream>>>(xinb, proj, zcb,
                                         dt_w + (size_t)i * DI * 16, dt_b + i * DI,
                                         A_log + (size_t)i * DI * 16, Dp + i * DI, ybf);

    dim3 g3(4, NT / 64);
    gemm_mfma64<<<g3, 256, 0, stream>>>(ybf, 512, wbl + WB_IN + WB_XP, h, 256, 256, 1);
  }

  head_kernel<<<NT / 4, 256, 0, stream>>>(h, fnorm_g, fnorm_b, head_w, head_b, (float*)d_out);
}

// Round 18
// 723.094 us; speedup vs baseline: 1.0145x; 1.0145x over previous
//
#include <hip/hip_runtime.h>
#include <math.h>

#define BSZ 16
#define LQ 1024
#define DM 256
#define DI 512
#define NT (BSZ*LQ)   // 16384 tokens

typedef __attribute__((ext_vector_type(8))) short short8;
typedef __attribute__((ext_vector_type(4))) short short4v;
typedef __attribute__((ext_vector_type(4))) float f32x4;

#define AS1(p) (const __attribute__((address_space(1))) void*)(p)
#define AS3(p) (__attribute__((address_space(3))) void*)(p)
#define GLOAD16(g, l) __builtin_amdgcn_global_load_lds(AS1(g), AS3(l), 16, 0, 0)

__device__ __forceinline__ short f2bf(float f) {
  union { float f; unsigned u; } a; a.f = f;
  unsigned r = (a.u + 0x7FFF + ((a.u >> 16) & 1)) >> 16;
  return (short)r;
}
__device__ __forceinline__ float bf2f(short s) {
  union { unsigned u; float f; } a; a.u = ((unsigned)(unsigned short)s) << 16;
  return a.f;
}

// ---------------- stem: conv1d(k=3,pad=1) + bias + relu -> h (bf16, B,L,DM) ----------------
__global__ void stem_kernel(const float* __restrict__ x, const float* __restrict__ w,
                            const float* __restrict__ bias, short* __restrict__ h) {
  int idx = blockIdx.x * 256 + threadIdx.x;   // over NT*DM = 4M
  int d = idx & 255;
  int l = (idx >> 8) & 1023;
  int b = idx >> 18;
  float acc = bias[d];
#pragma unroll
  for (int c = 0; c < 3; c++) {
    const float* xr = x + (size_t)(b * 3 + c) * LQ;
    const float* wr = w + (size_t)(d * 3 + c) * 3;
#pragma unroll
    for (int k = 0; k < 3; k++) {
      int t = l + k - 1;
      if (t >= 0 && t < LQ) acc += xr[t] * wr[k];
    }
  }
  h[idx] = f2bf(fmaxf(acc, 0.f));
}

// ---------------- weight conversion fp32 -> bf16 (x_proj padded to 64 rows) ----------------
#define WB_IN 262144          // 1024*256
#define WB_XP 32768           // 64*512 (rows >=48 zero)
#define WB_OUT 131072         // 256*512
#define WB_L (WB_IN + WB_XP + WB_OUT)

__global__ void convert_w(const float* __restrict__ in_w, const float* __restrict__ xp_w,
                          const float* __restrict__ out_w, short* __restrict__ wb) {
  int layer = blockIdx.y;
  int idx = blockIdx.x * 256 + threadIdx.x;
  short* dst = wb + (size_t)layer * WB_L;
  float v;
  if (idx < WB_IN) {
    v = in_w[(size_t)layer * WB_IN + idx];
  } else if (idx < WB_IN + WB_XP) {
    int k = idx - WB_IN; int row = k >> 9, col = k & 511;
    v = (row < 48) ? xp_w[(size_t)layer * 48 * 512 + row * 512 + col] : 0.f;
  } else {
    int k = idx - WB_IN - WB_XP;
    v = out_w[(size_t)layer * WB_OUT + k];
  }
  dst[idx] = f2bf(v);
}

// ---------------- layernorm over DM=256 (bf16 in) -> bf16 out; one WAVE per token ----------------
__global__ void ln_kernel(const short* __restrict__ x, const float* __restrict__ g,
                          const float* __restrict__ bv, short* __restrict__ o) {
  int token = blockIdx.x * 4 + (threadIdx.x >> 6);
  int lane = threadIdx.x & 63;
  short4v xv = *(const short4v*)(x + (size_t)token * DM + lane * 4);
  f32x4 v;
#pragma unroll
  for (int k = 0; k < 4; k++) v[k] = bf2f(xv[k]);
  float s = v[0] + v[1] + v[2] + v[3];
  float q = v[0]*v[0] + v[1]*v[1] + v[2]*v[2] + v[3]*v[3];
#pragma unroll
  for (int off = 32; off > 0; off >>= 1) {
    s += __shfl_xor(s, off, 64);
    q += __shfl_xor(q, off, 64);
  }
  float mu = s * (1.f / DM);
  float var = q * (1.f / DM) - mu * mu;
  float rs = rsqrtf(var + 1e-5f);
  f32x4 gg = *(const f32x4*)(g + lane * 4);
  f32x4 bb = *(const f32x4*)(bv + lane * 4);
  short4v ov;
#pragma unroll
  for (int k = 0; k < 4; k++) ov[k] = f2bf((v[k] - mu) * rs * gg[k] + bb[k]);
  *(short4v*)(o + (size_t)token * DM + lane * 4) = ov;
}

// ---------------- bf16 MFMA GEMM, 128x128 tile, BK=64 via two stacked 128x32 LDS blocks ----------------
// bf16 split store (for in_proj). K=256 -> 4 iters, 8 barriers.
__global__ __launch_bounds__(256) void gemm_mfma_s16(
    const short* __restrict__ A, int K,
    const short* __restrict__ W,
    short* __restrict__ C0, int ld0,
    short* __restrict__ C1, int ld1,
    int split, int N) {
  __shared__ short As[2][128 * 32];
  __shared__ short Bs[2][128 * 32];
  int tid = threadIdx.x;
  int wave = tid >> 6, lane = tid & 63;
  int bm = blockIdx.y * 128, bn = blockIdx.x * 128;
  int wm = (wave >> 1) * 64, wn = (wave & 1) * 64;

  f32x4 acc[4][4];
#pragma unroll
  for (int i = 0; i < 4; i++)
#pragma unroll
    for (int j = 0; j < 4; j++) { acc[i][j][0]=0.f; acc[i][j][1]=0.f; acc[i][j][2]=0.f; acc[i][j][3]=0.f; }

  int srow = lane >> 2;          // 16 rows per GLOAD16
  int scol = (lane & 3) * 8;     // 4 x 16B chunks per row of 32 shorts
  const short* Ag = A + (size_t)(bm + wave * 32 + srow) * K + scol;
  const short* Wg = W + (size_t)(bn + wave * 32 + srow) * K + scol;
  short* As0W = As[0] + wave * 32 * 32;
  short* As1W = As[1] + wave * 32 * 32;
  short* Bs0W = Bs[0] + wave * 32 * 32;
  short* Bs1W = Bs[1] + wave * 32 * 32;

  int fr = lane & 15;
  int kg = (lane >> 4) * 8;

  for (int k0 = 0; k0 < K; k0 += 64) {
    GLOAD16(Ag + k0,                         As0W);
    GLOAD16(Ag + k0 + (size_t)16 * K,        As0W + 16 * 32);
    GLOAD16(Ag + k0 + 32,                    As1W);
    GLOAD16(Ag + k0 + 32 + (size_t)16 * K,   As1W + 16 * 32);
    GLOAD16(Wg + k0,                         Bs0W);
    GLOAD16(Wg + k0 + (size_t)16 * K,        Bs0W + 16 * 32);
    GLOAD16(Wg + k0 + 32,                    Bs1W);
    GLOAD16(Wg + k0 + 32 + (size_t)16 * K,   Bs1W + 16 * 32);
    __syncthreads();

#pragma unroll
    for (int ks = 0; ks < 2; ks++) {
      short8 af[4], bf[4];
#pragma unroll
      for (int i = 0; i < 4; i++) af[i] = *(const short8*)&As[ks][(wm + i * 16 + fr) * 32 + kg];
#pragma unroll
      for (int j = 0; j < 4; j++) bf[j] = *(const short8*)&Bs[ks][(wn + j * 16 + fr) * 32 + kg];
#pragma unroll
      for (int i = 0; i < 4; i++)
#pragma unroll
        for (int j = 0; j < 4; j++)
          acc[i][j] = __builtin_amdgcn_mfma_f32_16x16x32_bf16(af[i], bf[j], acc[i][j], 0, 0, 0);
    }
    __syncthreads();
  }

  int cn = lane & 15, cr = (lane >> 4) * 4;
#pragma unroll
  for (int i = 0; i < 4; i++) {
    int row0 = bm + wm + i * 16 + cr;
#pragma unroll
    for (int j = 0; j < 4; j++) {
      int col = bn + wn + j * 16 + cn;
      if (col < N) {
#pragma unroll
        for (int r = 0; r < 4; r++) {
          short* p = (col < split) ? (C0 + (size_t)(row0 + r) * ld0 + col)
                                   : (C1 + (size_t)(row0 + r) * ld1 + (col - split));
          *p = f2bf(acc[i][j][r]);
        }
      }
    }
  }
}

// ---------------- fused conv+silu + x_proj GEMM; writes xinb as byproduct ----------------
// 32-token tiles, grid (1, NT/32) = 512 blocks (2/CU). Conv for the A-tile is computed
// inline between the W-tile global_load_lds issue and the barrier (hidden under DMA).
__global__ __launch_bounds__(256) void gemm2_conv(
    const short* __restrict__ xcb, const float* __restrict__ cw, const float* __restrict__ cb,
    const short* __restrict__ W, short* __restrict__ xinb, float* __restrict__ proj) {
  __shared__ short As[32 * 72];    // stride 72 shorts = 144B (16B-aligned rows)
  __shared__ short Bs[64 * 64];
  __shared__ float sCW[512 * 4];
  __shared__ float sCB[512];
  int tid = threadIdx.x;
  int wave = tid >> 6, lane = tid & 63;
  int bm = blockIdx.y * 32;
  int wm = (wave >> 1) * 16, wn = (wave & 1) * 32;

  for (int i = tid; i < 2048; i += 256) sCW[i] = cw[i];
  for (int i = tid; i < 512; i += 256) sCB[i] = cb[i];
  __syncthreads();

  f32x4 acc[2];
  acc[0] = (f32x4){0.f,0.f,0.f,0.f};
  acc[1] = (f32x4){0.f,0.f,0.f,0.f};

  int fr = lane & 15, kg = (lane >> 4) * 8;
  int r = tid >> 3;              // token row 0..31
  int cg = (tid & 7) * 8;        // channel group within 64
  int t = bm + r;
  int l = t & 1023;

  for (int k0 = 0; k0 < 512; k0 += 64) {
    // stage W tile (async DMA)
#pragma unroll
    for (int i = 0; i < 2; i++) {
      int c = tid + i * 256;
      GLOAD16(W + (size_t)(c >> 3) * 512 + k0 + (c & 7) * 8, Bs + c * 8);
    }
    // conv + silu for 8 channels of this token (overlaps the DMA)
    int ch0 = k0 + cg;
    short8 xv[4];
#pragma unroll
    for (int k = 0; k < 4; k++) {
      if (l + k - 3 >= 0) xv[k] = *(const short8*)(xcb + (size_t)(t + k - 3) * 512 + ch0);
      else xv[k] = (short8)0;
    }
    short8 ov;
#pragma unroll
    for (int e = 0; e < 8; e++) {
      f32x4 wv = *(const f32x4*)&sCW[(ch0 + e) * 4];
      float a = sCB[ch0 + e];
#pragma unroll
      for (int k = 0; k < 4; k++) a += bf2f(xv[k][e]) * wv[k];
      a = a / (1.f + __expf(-a));
      ov[e] = f2bf(a);
    }
    *(short8*)&As[r * 72 + cg] = ov;
    *(short8*)(xinb + (size_t)t * 512 + ch0) = ov;
    __syncthreads();

#pragma unroll
    for (int ks = 0; ks < 2; ks++) {
      short8 af = *(const short8*)&As[(wm + fr) * 72 + ks * 32 + kg];
#pragma unroll
      for (int j = 0; j < 2; j++) {
        short8 bf = *(const short8*)&Bs[(wn + j * 16 + fr) * 64 + ks * 32 + kg];
        acc[j] = __builtin_amdgcn_mfma_f32_16x16x32_bf16(af, bf, acc[j], 0, 0, 0);
      }
    }
    __syncthreads();
  }

  int cn = lane & 15, cr = (lane >> 4) * 4;
  int row0 = bm + wm + cr;
#pragma unroll
  for (int j = 0; j < 2; j++) {
    int col = wn + j * 16 + cn;
    if (col < 48) {
#pragma unroll
      for (int rr2 = 0; rr2 < 4; rr2++)
        proj[(size_t)(row0 + rr2) * 48 + col] = acc[j][rr2];
    }
  }
}

// ---------------- bf16 MFMA GEMM, 64x64 tile BK=64 (out_proj), bf16 C accum ----------------
__global__ __launch_bounds__(256) void gemm_mfma64(
    const short* __restrict__ A, int K,
    const short* __restrict__ W,
    short* __restrict__ C, int ldc, int N, int accum) {
  __shared__ short As[64 * 64];
  __shared__ short Bs[64 * 64];
  int tid = threadIdx.x;
  int wave = tid >> 6, lane = tid & 63;
  int bm = blockIdx.y * 64, bn = blockIdx.x * 64;
  int wm = (wave >> 1) * 32, wn = (wave & 1) * 32;

  f32x4 acc[2][2];
#pragma unroll
  for (int i = 0; i < 2; i++)
#pragma unroll
    for (int j = 0; j < 2; j++) { acc[i][j][0]=0.f; acc[i][j][1]=0.f; acc[i][j][2]=0.f; acc[i][j][3]=0.f; }

  const short* Ag = A + (size_t)bm * K;
  const short* Wg = W + (size_t)bn * K;
  int fr = lane & 15;
  int kg = (lane >> 4) * 8;

  for (int k0 = 0; k0 < K; k0 += 64) {
#pragma unroll
    for (int i = 0; i < 2; i++) {
      int c = tid + i * 256;
      int row = c >> 3, kk = (c & 7) * 8;
      GLOAD16(Ag + (size_t)row * K + k0 + kk, As + c * 8);
      GLOAD16(Wg + (size_t)row * K + k0 + kk, Bs + c * 8);
    }
    __syncthreads();

#pragma unroll
    for (int ks = 0; ks < 2; ks++) {
      short8 af[2], bf[2];
#pragma unroll
      for (int i = 0; i < 2; i++) af[i] = *(const short8*)&As[(wm + i * 16 + fr) * 64 + ks * 32 + kg];
#pragma unroll
      for (int j = 0; j < 2; j++) bf[j] = *(const short8*)&Bs[(wn + j * 16 + fr) * 64 + ks * 32 + kg];
#pragma unroll
      for (int i = 0; i < 2; i++)
#pragma unroll
        for (int j = 0; j < 2; j++)
          acc[i][j] = __builtin_amdgcn_mfma_f32_16x16x32_bf16(af[i], bf[j], acc[i][j], 0, 0, 0);
    }
    __syncthreads();
  }

  int cn = lane & 15, cr = (lane >> 4) * 4;
#pragma unroll
  for (int i = 0; i < 2; i++) {
    int row0 = bm + wm + i * 16 + cr;
#pragma unroll
    for (int j = 0; j < 2; j++) {
      int col = bn + wn + j * 16 + cn;
      if (col < N) {
#pragma unroll
        for (int r = 0; r < 4; r++) {
          float v = acc[i][j][r];
          short* p = C + (size_t)(row0 + r) * ldc + col;
          if (accum) v += bf2f(*p);
          *p = f2bf(v);
        }
      }
    }
  }
}

// ---------------- 16-lane sum via DPP ----------------
template <int CTRL>
__device__ __forceinline__ float dpp_add(float x) {
  int yi = __builtin_amdgcn_update_dpp(0, __float_as_int(x), CTRL, 0xF, 0xF, true);
  return x + __int_as_float(yi);
}
__device__ __forceinline__ float sum16(float x) {
  x = dpp_add<0xB1>(x);   // quad_perm xor1
  x = dpp_add<0x4E>(x);   // quad_perm xor2
  x = dpp_add<0x124>(x);  // row_ror:4
  x = dpp_add<0x128>(x);  // row_ror:8
  return x;
}

// ---------------- fused delta-proj + selective scan + Dp skip + silu(z) gate ----------------
// TCH=32, 3x __syncthreads per chunk (R12-proven).
#define TCH 32
__global__ __launch_bounds__(256) void scan_kernel(
    const short* __restrict__ xinb, const float* __restrict__ proj,
    const short* __restrict__ zc,
    const float* __restrict__ dt_w, const float* __restrict__ dt_b,
    const float* __restrict__ A_log, const float* __restrict__ Dp,
    short* __restrict__ ybf) {
  int b  = blockIdx.x >> 5;
  int d0 = (blockIdx.x & 31) << 4;
  int tid = threadIdx.x;
  int ci = tid >> 4;
  int s  = tid & 15;
  int d = d0 + ci;

  __shared__ float sDt[32 * 20];
  __shared__ float sBT[16 * 36];
  __shared__ float sCT[16 * 36];
  __shared__ float sUT[16 * 36];
  __shared__ float sDU[16 * 36];
  __shared__ float sDel[16 * 36];
  __shared__ float sY[32 * 17];

  float Av = -__expf(A_log[(size_t)d * 16 + s]);
  f32x4 wv4[4];
#pragma unroll
  for (int k = 0; k < 4; k++) wv4[k] = *(const f32x4*)&dt_w[(size_t)d * 16 + k * 4];
  float db = dt_b[d];
  float Ddj = Dp[d0 + s];
  float h = 0.f;

  const float* projb = proj + (size_t)b * LQ * 48;
  const short* xinbb = xinb + (size_t)b * LQ * 512 + d0;
  const short* zcb   = zc   + (size_t)b * LQ * 512 + d0;
  short* ybb         = ybf  + (size_t)b * LQ * 512 + d0;

  int tt = tid >> 4, j = tid & 15;

  int tr[6], rr[6];
#pragma unroll
  for (int k = 0; k < 6; k++) { int idx = tid + k * 256; tr[k] = idx / 48; rr[k] = idx - tr[k] * 48; }

  float uv0, uv1, zv0, zv1;
  {
    float pjv[6];
#pragma unroll
    for (int k = 0; k < 6; k++) pjv[k] = projb[tid + k * 256];
    uv0 = bf2f(xinbb[(size_t)tt * 512 + j]);
    uv1 = bf2f(xinbb[(size_t)(tt + 16) * 512 + j]);
    zv0 = bf2f(zcb[(size_t)tt * 512 + j]);
    zv1 = bf2f(zcb[(size_t)(tt + 16) * 512 + j]);
#pragma unroll
    for (int k = 0; k < 6; k++) {
      int r = rr[k], t = tr[k];
      if (r < 16)      sDt[t * 20 + r] = pjv[k];
      else if (r < 32) sBT[(r - 16) * 36 + t] = pjv[k];
      else             sCT[(r - 32) * 36 + t] = pjv[k];
    }
    sUT[j * 36 + tt] = uv0;
    sUT[j * 36 + tt + 16] = uv1;
  }
  __syncthreads();

  const int NCH = LQ / TCH;
  for (int c = 0; c < NCH; c++) {
    int t0 = c * TCH;

    float pjn[6], un0 = 0.f, un1 = 0.f, zn0 = 0.f, zn1 = 0.f;
    if (c + 1 < NCH) {
      const float* g = projb + (t0 + TCH) * 48;
#pragma unroll
      for (int k = 0; k < 6; k++) pjn[k] = g[tid + k * 256];
      un0 = bf2f(xinbb[(size_t)(t0 + TCH + tt) * 512 + j]);
      un1 = bf2f(xinbb[(size_t)(t0 + TCH + tt + 16) * 512 + j]);
      zn0 = bf2f(zcb[(size_t)(t0 + TCH + tt) * 512 + j]);
      zn1 = bf2f(zcb[(size_t)(t0 + TCH + tt + 16) * 512 + j]);
    }

    {
      f32x4 a0 = *(const f32x4*)&sDt[s * 20 + 0];
      f32x4 a1 = *(const f32x4*)&sDt[s * 20 + 4];
      f32x4 a2 = *(const f32x4*)&sDt[s * 20 + 8];
      f32x4 a3 = *(const f32x4*)&sDt[s * 20 + 12];
      f32x4 b0 = *(const f32x4*)&sDt[(s + 16) * 20 + 0];
      f32x4 b1 = *(const f32x4*)&sDt[(s + 16) * 20 + 4];
      f32x4 b2 = *(const f32x4*)&sDt[(s + 16) * 20 + 8];
      f32x4 b3 = *(const f32x4*)&sDt[(s + 16) * 20 + 12];
      float dt0 = db, dt1 = db;
#pragma unroll
      for (int q = 0; q < 4; q++) {
        dt0 += a0[q] * wv4[0][q] + a1[q] * wv4[1][q] + a2[q] * wv4[2][q] + a3[q] * wv4[3][q];
        dt1 += b0[q] * wv4[0][q] + b1[q] * wv4[1][q] + b2[q] * wv4[2][q] + b3[q] * wv4[3][q];
      }
      float de0 = (dt0 > 15.f) ? dt0 : __logf(1.f + __expf(dt0));
      float de1 = (dt1 > 15.f) ? dt1 : __logf(1.f + __expf(dt1));
      float u0 = sUT[ci * 36 + s];
      float u1 = sUT[ci * 36 + s + 16];
      sDel[ci * 36 + s]      = de0;
      sDel[ci * 36 + s + 16] = de1;
      sDU[ci * 36 + s]       = de0 * u0;
      sDU[ci * 36 + s + 16]  = de1 * u1;
    }
    __syncthreads();   // B1

    {
      float ee[TCH], cin[TCH];
      f32x4 ct[8];
      {
        f32x4 dl[8], du8[8], bt[8];
#pragma unroll
        for (int k = 0; k < 8; k++) {
          dl[k]  = *(const f32x4*)&sDel[ci * 36 + k * 4];
          du8[k] = *(const f32x4*)&sDU[ci * 36 + k * 4];
          bt[k]  = *(const f32x4*)&sBT[s * 36 + k * 4];
          ct[k]  = *(const f32x4*)&sCT[s * 36 + k * 4];
        }
#pragma unroll
        for (int t = 0; t < TCH; t++) {
          ee[t] = __expf(dl[t >> 2][t & 3] * Av);
          cin[t] = du8[t >> 2][t & 3] * bt[t >> 2][t & 3];
        }
      }
      float pv0 = 0.f, pv1 = 0.f;
#pragma unroll
      for (int t = 0; t < TCH; t++) {
        h = h * ee[t] + cin[t];
        float p = sum16(h * ct[t >> 2][t & 3]);
        if (t < 16) pv0 = (s == t) ? p : pv0;
        else        pv1 = (s == (t - 16)) ? p : pv1;
      }
      sY[s * 17 + ci] = pv0;
      sY[(s + 16) * 17 + ci] = pv1;
    }
    __syncthreads();   // B2

    {
      float p0 = sY[tt * 17 + j];
      float p1 = sY[(tt + 16) * 17 + j];
      float y0 = p0 + uv0 * Ddj;
      float y1 = p1 + uv1 * Ddj;
      float g0 = zv0 / (1.f + __expf(-zv0));
      float g1 = zv1 / (1.f + __expf(-zv1));
      ybb[(size_t)(t0 + tt) * 512 + j] = f2bf(y0 * g0);
      ybb[(size_t)(t0 + tt + 16) * 512 + j] = f2bf(y1 * g1);
    }
    if (c + 1 < NCH) {
#pragma unroll
      for (int k = 0; k < 6; k++) {
        int r = rr[k], t = tr[k];
        if (r < 16)      sDt[t * 20 + r] = pjn[k];
        else if (r < 32) sBT[(r - 16) * 36 + t] = pjn[k];
        else             sCT[(r - 32) * 36 + t] = pjn[k];
      }
      sUT[j * 36 + tt] = un0;
      sUT[j * 36 + tt + 16] = un1;
      uv0 = un0; uv1 = un1; zv0 = zn0; zv1 = zn1;
    }
    __syncthreads();   // B3
  }
}

// ---------------- final LN + head dot + sigmoid; one WAVE per token (bf16 h) ----------------
__global__ void head_kernel(const short* __restrict__ h, const float* __restrict__ g,
                            const float* __restrict__ bv, const float* __restrict__ hw,
                            const float* __restrict__ hb, float* __restrict__ out) {
  int token = blockIdx.x * 4 + (threadIdx.x >> 6);
  int lane = threadIdx.x & 63;
  short4v xv = *(const short4v*)(h + (size_t)token * DM + lane * 4);
  f32x4 v;
#pragma unroll
  for (int k = 0; k < 4; k++) v[k] = bf2f(xv[k]);
  float s = v[0] + v[1] + v[2] + v[3];
  float q = v[0]*v[0] + v[1]*v[1] + v[2]*v[2] + v[3]*v[3];
#pragma unroll
  for (int off = 32; off > 0; off >>= 1) {
    s += __shfl_xor(s, off, 64);
    q += __shfl_xor(q, off, 64);
  }
  float mu = s * (1.f / DM);
  float rs = rsqrtf(q * (1.f / DM) - mu * mu + 1e-5f);
  f32x4 gg = *(const f32x4*)(g + lane * 4);
  f32x4 bb = *(const f32x4*)(bv + lane * 4);
  f32x4 ww = *(const f32x4*)(hw + lane * 4);
  float c = 0.f;
#pragma unroll
  for (int k = 0; k < 4; k++) c += ((v[k] - mu) * rs * gg[k] + bb[k]) * ww[k];
#pragma unroll
  for (int off = 32; off > 0; off >>= 1) c += __shfl_xor(c, off, 64);
  if (lane == 0) out[token] = 1.f / (1.f + __expf(-(c + hb[0])));
}

extern "C" void kernel_launch(void* const* d_in, const int* in_sizes, int n_in,
                              void* d_out, int out_size, void* d_ws, size_t ws_size,
                              hipStream_t stream) {
  const float* x        = (const float*)d_in[0];
  const float* stem_w   = (const float*)d_in[1];
  const float* stem_b   = (const float*)d_in[2];
  const float* norm_g   = (const float*)d_in[3];
  const float* norm_b   = (const float*)d_in[4];
  const float* in_proj_w= (const float*)d_in[5];
  const float* conv_w   = (const float*)d_in[6];
  const float* conv_b   = (const float*)d_in[7];
  const float* x_proj_w = (const float*)d_in[8];
  const float* dt_w     = (const float*)d_in[9];
  const float* dt_b     = (const float*)d_in[10];
  const float* A_log    = (const float*)d_in[11];
  const float* Dp       = (const float*)d_in[12];
  const float* out_w    = (const float*)d_in[13];
  const float* fnorm_g  = (const float*)d_in[14];
  const float* fnorm_b  = (const float*)d_in[15];
  const float* head_w   = (const float*)d_in[16];
  const float* head_b   = (const float*)d_in[17];

  char* base = (char*)d_ws;
  short* h    = (short*)(base);                           // 8 MB (bf16 residual)
  short* xcb  = (short*)(base + ((size_t)16 << 20));      // 16 MB
  short* zcb  = (short*)(base + ((size_t)32 << 20));      // 16 MB
  short* xnb  = (short*)(base + ((size_t)48 << 20));      // 8 MB
  short* xinb = (short*)(base + ((size_t)56 << 20));      // 16 MB
  short* ybf  = (short*)(base + ((size_t)72 << 20));      // 16 MB
  float* proj = (float*)(base + ((size_t)88 << 20));      // 3 MB
  short* wb   = (short*)(base + ((size_t)91 << 20));      // 3.5 MB

  stem_kernel<<<NT, 256, 0, stream>>>(x, stem_w, stem_b, h);

  dim3 gcw(WB_L / 256, 4);
  convert_w<<<gcw, 256, 0, stream>>>(in_proj_w, x_proj_w, out_w, wb);

  for (int i = 0; i < 4; i++) {
    const short* wbl = wb + (size_t)i * WB_L;

    ln_kernel<<<NT / 4, 256, 0, stream>>>(h, norm_g + i * DM, norm_b + i * DM, xnb);

    dim3 g1(8, NT / 128);
    gemm_mfma_s16<<<g1, 256, 0, stream>>>(xnb, 256, wbl, xcb, 512, zcb, 512, 512, 1024);

    dim3 g2(1, NT / 32);
    gemm2_conv<<<g2, 256, 0, stream>>>(xcb, conv_w + i * DI * 4, conv_b + i * DI,
                                       wbl + WB_IN, xinb, proj);

    scan_kernel<<<512, 256, 0, stream>>>(xinb, proj, zcb,
                                         dt_w + (size_t)i * DI * 16, dt_b + i * DI,
                                         A_log + (size_t)i * DI * 16, Dp + i * DI, ybf);

    dim3 g3(4, NT / 64);
    gemm_mfma64<<<g3, 256, 0, stream>>>(ybf, 512, wbl + WB_IN + WB_XP, h, 256, 256, 1);
  }

  head_kernel<<<NT / 4, 256, 0, stream>>>(h, fnorm_g, fnorm_b, head_w, head_b, (float*)d_out);
}

// Round 19
// 718.892 us; speedup vs baseline: 1.0204x; 1.0058x over previous
//
#include <hip/hip_runtime.h>
#include <math.h>

#define BSZ 16
#define LQ 1024
#define DM 256
#define DI 512
#define NT (BSZ*LQ)   // 16384 tokens

typedef __attribute__((ext_vector_type(8))) short short8;
typedef __attribute__((ext_vector_type(4))) short short4v;
typedef __attribute__((ext_vector_type(4))) float f32x4;

#define AS1(p) (const __attribute__((address_space(1))) void*)(p)
#define AS3(p) (__attribute__((address_space(3))) void*)(p)
#define GLOAD16(g, l) __builtin_amdgcn_global_load_lds(AS1(g), AS3(l), 16, 0, 0)

__device__ __forceinline__ short f2bf(float f) {
  union { float f; unsigned u; } a; a.f = f;
  unsigned r = (a.u + 0x7FFF + ((a.u >> 16) & 1)) >> 16;
  return (short)r;
}
__device__ __forceinline__ float bf2f(short s) {
  union { unsigned u; float f; } a; a.u = ((unsigned)(unsigned short)s) << 16;
  return a.f;
}

// ---------------- stem: conv1d(k=3,pad=1) + bias + relu -> h (bf16, B,L,DM) ----------------
__global__ void stem_kernel(const float* __restrict__ x, const float* __restrict__ w,
                            const float* __restrict__ bias, short* __restrict__ h) {
  int idx = blockIdx.x * 256 + threadIdx.x;   // over NT*DM = 4M
  int d = idx & 255;
  int l = (idx >> 8) & 1023;
  int b = idx >> 18;
  float acc = bias[d];
#pragma unroll
  for (int c = 0; c < 3; c++) {
    const float* xr = x + (size_t)(b * 3 + c) * LQ;
    const float* wr = w + (size_t)(d * 3 + c) * 3;
#pragma unroll
    for (int k = 0; k < 3; k++) {
      int t = l + k - 1;
      if (t >= 0 && t < LQ) acc += xr[t] * wr[k];
    }
  }
  h[idx] = f2bf(fmaxf(acc, 0.f));
}

// ---------------- weight conversion fp32 -> bf16 (x_proj padded to 64 rows) ----------------
#define WB_IN 262144          // 1024*256
#define WB_XP 32768           // 64*512 (rows >=48 zero)
#define WB_OUT 131072         // 256*512
#define WB_L (WB_IN + WB_XP + WB_OUT)

__global__ void convert_w(const float* __restrict__ in_w, const float* __restrict__ xp_w,
                          const float* __restrict__ out_w, short* __restrict__ wb) {
  int layer = blockIdx.y;
  int idx = blockIdx.x * 256 + threadIdx.x;
  short* dst = wb + (size_t)layer * WB_L;
  float v;
  if (idx < WB_IN) {
    v = in_w[(size_t)layer * WB_IN + idx];
  } else if (idx < WB_IN + WB_XP) {
    int k = idx - WB_IN; int row = k >> 9, col = k & 511;
    v = (row < 48) ? xp_w[(size_t)layer * 48 * 512 + row * 512 + col] : 0.f;
  } else {
    int k = idx - WB_IN - WB_XP;
    v = out_w[(size_t)layer * WB_OUT + k];
  }
  dst[idx] = f2bf(v);
}

// ---------------- layernorm over DM=256 (bf16 in) -> bf16 out; one WAVE per token ----------------
__global__ void ln_kernel(const short* __restrict__ x, const float* __restrict__ g,
                          const float* __restrict__ bv, short* __restrict__ o) {
  int token = blockIdx.x * 4 + (threadIdx.x >> 6);
  int lane = threadIdx.x & 63;
  short4v xv = *(const short4v*)(x + (size_t)token * DM + lane * 4);
  f32x4 v;
#pragma unroll
  for (int k = 0; k < 4; k++) v[k] = bf2f(xv[k]);
  float s = v[0] + v[1] + v[2] + v[3];
  float q = v[0]*v[0] + v[1]*v[1] + v[2]*v[2] + v[3]*v[3];
#pragma unroll
  for (int off = 32; off > 0; off >>= 1) {
    s += __shfl_xor(s, off, 64);
    q += __shfl_xor(q, off, 64);
  }
  float mu = s * (1.f / DM);
  float var = q * (1.f / DM) - mu * mu;
  float rs = rsqrtf(var + 1e-5f);
  f32x4 gg = *(const f32x4*)(g + lane * 4);
  f32x4 bb = *(const f32x4*)(bv + lane * 4);
  short4v ov;
#pragma unroll
  for (int k = 0; k < 4; k++) ov[k] = f2bf((v[k] - mu) * rs * gg[k] + bb[k]);
  *(short4v*)(o + (size_t)token * DM + lane * 4) = ov;
}

// ---------------- bf16 MFMA GEMM, 128x128 tile, BK=64; SWAPPED operands ----------------
// mfma(bf, af) -> D[weightcol][token]: each lane's 4 regs = 4 consecutive out-cols of one
// token -> contiguous short4 stores. bf16 split store (in_proj). K=256 -> 4 iters.
__global__ __launch_bounds__(256) void gemm_mfma_s16(
    const short* __restrict__ A, int K,
    const short* __restrict__ W,
    short* __restrict__ C0, int ld0,
    short* __restrict__ C1, int ld1,
    int split, int N) {
  __shared__ short As[2][128 * 32];
  __shared__ short Bs[2][128 * 32];
  int tid = threadIdx.x;
  int wave = tid >> 6, lane = tid & 63;
  int bm = blockIdx.y * 128, bn = blockIdx.x * 128;
  int wm = (wave >> 1) * 64, wn = (wave & 1) * 64;

  f32x4 acc[4][4];
#pragma unroll
  for (int i = 0; i < 4; i++)
#pragma unroll
    for (int j = 0; j < 4; j++) { acc[i][j][0]=0.f; acc[i][j][1]=0.f; acc[i][j][2]=0.f; acc[i][j][3]=0.f; }

  int srow = lane >> 2;          // 16 rows per GLOAD16
  int scol = (lane & 3) * 8;     // 4 x 16B chunks per row of 32 shorts
  const short* Ag = A + (size_t)(bm + wave * 32 + srow) * K + scol;
  const short* Wg = W + (size_t)(bn + wave * 32 + srow) * K + scol;
  short* As0W = As[0] + wave * 32 * 32;
  short* As1W = As[1] + wave * 32 * 32;
  short* Bs0W = Bs[0] + wave * 32 * 32;
  short* Bs1W = Bs[1] + wave * 32 * 32;

  int fr = lane & 15;
  int kg = (lane >> 4) * 8;

  for (int k0 = 0; k0 < K; k0 += 64) {
    GLOAD16(Ag + k0,                         As0W);
    GLOAD16(Ag + k0 + (size_t)16 * K,        As0W + 16 * 32);
    GLOAD16(Ag + k0 + 32,                    As1W);
    GLOAD16(Ag + k0 + 32 + (size_t)16 * K,   As1W + 16 * 32);
    GLOAD16(Wg + k0,                         Bs0W);
    GLOAD16(Wg + k0 + (size_t)16 * K,        Bs0W + 16 * 32);
    GLOAD16(Wg + k0 + 32,                    Bs1W);
    GLOAD16(Wg + k0 + 32 + (size_t)16 * K,   Bs1W + 16 * 32);
    __syncthreads();

#pragma unroll
    for (int ks = 0; ks < 2; ks++) {
      short8 af[4], bf[4];
#pragma unroll
      for (int i = 0; i < 4; i++) af[i] = *(const short8*)&As[ks][(wm + i * 16 + fr) * 32 + kg];
#pragma unroll
      for (int j = 0; j < 4; j++) bf[j] = *(const short8*)&Bs[ks][(wn + j * 16 + fr) * 32 + kg];
#pragma unroll
      for (int i = 0; i < 4; i++)
#pragma unroll
        for (int j = 0; j < 4; j++)
          acc[i][j] = __builtin_amdgcn_mfma_f32_16x16x32_bf16(bf[j], af[i], acc[i][j], 0, 0, 0);
    }
    __syncthreads();
  }

  // swapped D layout: token = lane&15 (within i-tile), out-col run = (lane>>4)*4 (within j-tile)
  int tn = lane & 15, cr = (lane >> 4) * 4;
#pragma unroll
  for (int i = 0; i < 4; i++) {
    int token = bm + wm + i * 16 + tn;
#pragma unroll
    for (int j = 0; j < 4; j++) {
      int col0 = bn + wn + j * 16 + cr;      // 4-aligned; split=512 is 4-aligned -> no crossing
      short4v ov;
#pragma unroll
      for (int r = 0; r < 4; r++) ov[r] = f2bf(acc[i][j][r]);
      short* p = (col0 < split) ? (C0 + (size_t)token * ld0 + col0)
                                : (C1 + (size_t)token * ld1 + (col0 - split));
      *(short4v*)p = ov;
    }
  }
}

// ---------------- fused conv+silu + x_proj GEMM; writes xinb as byproduct ----------------
// 32-token tiles, grid (1, NT/32) = 512 blocks (2/CU). Conv for the A-tile is computed
// inline between the W-tile global_load_lds issue and the barrier (hidden under DMA).
__global__ __launch_bounds__(256) void gemm2_conv(
    const short* __restrict__ xcb, const float* __restrict__ cw, const float* __restrict__ cb,
    const short* __restrict__ W, short* __restrict__ xinb, float* __restrict__ proj) {
  __shared__ short As[32 * 72];    // stride 72 shorts = 144B (16B-aligned rows)
  __shared__ short Bs[64 * 64];
  __shared__ float sCW[512 * 4];
  __shared__ float sCB[512];
  int tid = threadIdx.x;
  int wave = tid >> 6, lane = tid & 63;
  int bm = blockIdx.y * 32;
  int wm = (wave >> 1) * 16, wn = (wave & 1) * 32;

  for (int i = tid; i < 2048; i += 256) sCW[i] = cw[i];
  for (int i = tid; i < 512; i += 256) sCB[i] = cb[i];
  __syncthreads();

  f32x4 acc[2];
  acc[0] = (f32x4){0.f,0.f,0.f,0.f};
  acc[1] = (f32x4){0.f,0.f,0.f,0.f};

  int fr = lane & 15, kg = (lane >> 4) * 8;
  int r = tid >> 3;              // token row 0..31
  int cg = (tid & 7) * 8;        // channel group within 64
  int t = bm + r;
  int l = t & 1023;

  for (int k0 = 0; k0 < 512; k0 += 64) {
    // stage W tile (async DMA)
#pragma unroll
    for (int i = 0; i < 2; i++) {
      int c = tid + i * 256;
      GLOAD16(W + (size_t)(c >> 3) * 512 + k0 + (c & 7) * 8, Bs + c * 8);
    }
    // conv + silu for 8 channels of this token (overlaps the DMA)
    int ch0 = k0 + cg;
    short8 xv[4];
#pragma unroll
    for (int k = 0; k < 4; k++) {
      if (l + k - 3 >= 0) xv[k] = *(const short8*)(xcb + (size_t)(t + k - 3) * 512 + ch0);
      else xv[k] = (short8)0;
    }
    short8 ov;
#pragma unroll
    for (int e = 0; e < 8; e++) {
      f32x4 wv = *(const f32x4*)&sCW[(ch0 + e) * 4];
      float a = sCB[ch0 + e];
#pragma unroll
      for (int k = 0; k < 4; k++) a += bf2f(xv[k][e]) * wv[k];
      a = a / (1.f + __expf(-a));
      ov[e] = f2bf(a);
    }
    *(short8*)&As[r * 72 + cg] = ov;
    *(short8*)(xinb + (size_t)t * 512 + ch0) = ov;
    __syncthreads();

#pragma unroll
    for (int ks = 0; ks < 2; ks++) {
      short8 af = *(const short8*)&As[(wm + fr) * 72 + ks * 32 + kg];
#pragma unroll
      for (int j = 0; j < 2; j++) {
        short8 bf = *(const short8*)&Bs[(wn + j * 16 + fr) * 64 + ks * 32 + kg];
        acc[j] = __builtin_amdgcn_mfma_f32_16x16x32_bf16(af, bf, acc[j], 0, 0, 0);
      }
    }
    __syncthreads();
  }

  int cn = lane & 15, cr = (lane >> 4) * 4;
  int row0 = bm + wm + cr;
#pragma unroll
  for (int j = 0; j < 2; j++) {
    int col = wn + j * 16 + cn;
    if (col < 48) {
#pragma unroll
      for (int rr2 = 0; rr2 < 4; rr2++)
        proj[(size_t)(row0 + rr2) * 48 + col] = acc[j][rr2];
    }
  }
}

// ---------------- bf16 MFMA GEMM, 64x64 tile BK=64 (out_proj), bf16 C accum; SWAPPED ----------------
__global__ __launch_bounds__(256) void gemm_mfma64(
    const short* __restrict__ A, int K,
    const short* __restrict__ W,
    short* __restrict__ C, int ldc, int N, int accum) {
  __shared__ short As[64 * 64];
  __shared__ short Bs[64 * 64];
  int tid = threadIdx.x;
  int wave = tid >> 6, lane = tid & 63;
  int bm = blockIdx.y * 64, bn = blockIdx.x * 64;
  int wm = (wave >> 1) * 32, wn = (wave & 1) * 32;

  f32x4 acc[2][2];
#pragma unroll
  for (int i = 0; i < 2; i++)
#pragma unroll
    for (int j = 0; j < 2; j++) { acc[i][j][0]=0.f; acc[i][j][1]=0.f; acc[i][j][2]=0.f; acc[i][j][3]=0.f; }

  const short* Ag = A + (size_t)bm * K;
  const short* Wg = W + (size_t)bn * K;
  int fr = lane & 15;
  int kg = (lane >> 4) * 8;

  for (int k0 = 0; k0 < K; k0 += 64) {
#pragma unroll
    for (int i = 0; i < 2; i++) {
      int c = tid + i * 256;
      int row = c >> 3, kk = (c & 7) * 8;
      GLOAD16(Ag + (size_t)row * K + k0 + kk, As + c * 8);
      GLOAD16(Wg + (size_t)row * K + k0 + kk, Bs + c * 8);
    }
    __syncthreads();

#pragma unroll
    for (int ks = 0; ks < 2; ks++) {
      short8 af[2], bf[2];
#pragma unroll
      for (int i = 0; i < 2; i++) af[i] = *(const short8*)&As[(wm + i * 16 + fr) * 64 + ks * 32 + kg];
#pragma unroll
      for (int j = 0; j < 2; j++) bf[j] = *(const short8*)&Bs[(wn + j * 16 + fr) * 64 + ks * 32 + kg];
#pragma unroll
      for (int i = 0; i < 2; i++)
#pragma unroll
        for (int j = 0; j < 2; j++)
          acc[i][j] = __builtin_amdgcn_mfma_f32_16x16x32_bf16(bf[j], af[i], acc[i][j], 0, 0, 0);
    }
    __syncthreads();
  }

  // swapped D layout: token = lane&15, out-col run = (lane>>4)*4
  int tn = lane & 15, cr = (lane >> 4) * 4;
#pragma unroll
  for (int i = 0; i < 2; i++) {
    int token = bm + wm + i * 16 + tn;
#pragma unroll
    for (int j = 0; j < 2; j++) {
      int col0 = bn + wn + j * 16 + cr;
      if (col0 < N) {
        short* p = C + (size_t)token * ldc + col0;
        short4v ov;
        if (accum) {
          short4v old = *(const short4v*)p;
#pragma unroll
          for (int r = 0; r < 4; r++) ov[r] = f2bf(acc[i][j][r] + bf2f(old[r]));
        } else {
#pragma unroll
          for (int r = 0; r < 4; r++) ov[r] = f2bf(acc[i][j][r]);
        }
        *(short4v*)p = ov;
      }
    }
  }
}

// ---------------- 16-lane sum via DPP ----------------
template <int CTRL>
__device__ __forceinline__ float dpp_add(float x) {
  int yi = __builtin_amdgcn_update_dpp(0, __float_as_int(x), CTRL, 0xF, 0xF, true);
  return x + __int_as_float(yi);
}
__device__ __forceinline__ float sum16(float x) {
  x = dpp_add<0xB1>(x);   // quad_perm xor1
  x = dpp_add<0x4E>(x);   // quad_perm xor2
  x = dpp_add<0x124>(x);  // row_ror:4
  x = dpp_add<0x128>(x);  // row_ror:8
  return x;
}

// ---------------- fused delta-proj + selective scan + Dp skip + silu(z) gate ----------------
// TCH=32, 3x __syncthreads per chunk (R12-proven).
#define TCH 32
__global__ __launch_bounds__(256) void scan_kernel(
    const short* __restrict__ xinb, const float* __restrict__ proj,
    const short* __restrict__ zc,
    const float* __restrict__ dt_w, const float* __restrict__ dt_b,
    const float* __restrict__ A_log, const float* __restrict__ Dp,
    short* __restrict__ ybf) {
  int b  = blockIdx.x >> 5;
  int d0 = (blockIdx.x & 31) << 4;
  int tid = threadIdx.x;
  int ci = tid >> 4;
  int s  = tid & 15;
  int d = d0 + ci;

  __shared__ float sDt[32 * 20];
  __shared__ float sBT[16 * 36];
  __shared__ float sCT[16 * 36];
  __shared__ float sUT[16 * 36];
  __shared__ float sDU[16 * 36];
  __shared__ float sDel[16 * 36];
  __shared__ float sY[32 * 17];

  float Av = -__expf(A_log[(size_t)d * 16 + s]);
  f32x4 wv4[4];
#pragma unroll
  for (int k = 0; k < 4; k++) wv4[k] = *(const f32x4*)&dt_w[(size_t)d * 16 + k * 4];
  float db = dt_b[d];
  float Ddj = Dp[d0 + s];
  float h = 0.f;

  const float* projb = proj + (size_t)b * LQ * 48;
  const short* xinbb = xinb + (size_t)b * LQ * 512 + d0;
  const short* zcb   = zc   + (size_t)b * LQ * 512 + d0;
  short* ybb         = ybf  + (size_t)b * LQ * 512 + d0;

  int tt = tid >> 4, j = tid & 15;

  int tr[6], rr[6];
#pragma unroll
  for (int k = 0; k < 6; k++) { int idx = tid + k * 256; tr[k] = idx / 48; rr[k] = idx - tr[k] * 48; }

  float uv0, uv1, zv0, zv1;
  {
    float pjv[6];
#pragma unroll
    for (int k = 0; k < 6; k++) pjv[k] = projb[tid + k * 256];
    uv0 = bf2f(xinbb[(size_t)tt * 512 + j]);
    uv1 = bf2f(xinbb[(size_t)(tt + 16) * 512 + j]);
    zv0 = bf2f(zcb[(size_t)tt * 512 + j]);
    zv1 = bf2f(zcb[(size_t)(tt + 16) * 512 + j]);
#pragma unroll
    for (int k = 0; k < 6; k++) {
      int r = rr[k], t = tr[k];
      if (r < 16)      sDt[t * 20 + r] = pjv[k];
      else if (r < 32) sBT[(r - 16) * 36 + t] = pjv[k];
      else             sCT[(r - 32) * 36 + t] = pjv[k];
    }
    sUT[j * 36 + tt] = uv0;
    sUT[j * 36 + tt + 16] = uv1;
  }
  __syncthreads();

  const int NCH = LQ / TCH;
  for (int c = 0; c < NCH; c++) {
    int t0 = c * TCH;

    float pjn[6], un0 = 0.f, un1 = 0.f, zn0 = 0.f, zn1 = 0.f;
    if (c + 1 < NCH) {
      const float* g = projb + (t0 + TCH) * 48;
#pragma unroll
      for (int k = 0; k < 6; k++) pjn[k] = g[tid + k * 256];
      un0 = bf2f(xinbb[(size_t)(t0 + TCH + tt) * 512 + j]);
      un1 = bf2f(xinbb[(size_t)(t0 + TCH + tt + 16) * 512 + j]);
      zn0 = bf2f(zcb[(size_t)(t0 + TCH + tt) * 512 + j]);
      zn1 = bf2f(zcb[(size_t)(t0 + TCH + tt + 16) * 512 + j]);
    }

    {
      f32x4 a0 = *(const f32x4*)&sDt[s * 20 + 0];
      f32x4 a1 = *(const f32x4*)&sDt[s * 20 + 4];
      f32x4 a2 = *(const f32x4*)&sDt[s * 20 + 8];
      f32x4 a3 = *(const f32x4*)&sDt[s * 20 + 12];
      f32x4 b0 = *(const f32x4*)&sDt[(s + 16) * 20 + 0];
      f32x4 b1 = *(const f32x4*)&sDt[(s + 16) * 20 + 4];
      f32x4 b2 = *(const f32x4*)&sDt[(s + 16) * 20 + 8];
      f32x4 b3 = *(const f32x4*)&sDt[(s + 16) * 20 + 12];
      float dt0 = db, dt1 = db;
#pragma unroll
      for (int q = 0; q < 4; q++) {
        dt0 += a0[q] * wv4[0][q] + a1[q] * wv4[1][q] + a2[q] * wv4[2][q] + a3[q] * wv4[3][q];
        dt1 += b0[q] * wv4[0][q] + b1[q] * wv4[1][q] + b2[q] * wv4[2][q] + b3[q] * wv4[3][q];
      }
      float de0 = (dt0 > 15.f) ? dt0 : __logf(1.f + __expf(dt0));
      float de1 = (dt1 > 15.f) ? dt1 : __logf(1.f + __expf(dt1));
      float u0 = sUT[ci * 36 + s];
      float u1 = sUT[ci * 36 + s + 16];
      sDel[ci * 36 + s]      = de0;
      sDel[ci * 36 + s + 16] = de1;
      sDU[ci * 36 + s]       = de0 * u0;
      sDU[ci * 36 + s + 16]  = de1 * u1;
    }
    __syncthreads();   // B1

    {
      float ee[TCH], cin[TCH];
      f32x4 ct[8];
      {
        f32x4 dl[8], du8[8], bt[8];
#pragma unroll
        for (int k = 0; k < 8; k++) {
          dl[k]  = *(const f32x4*)&sDel[ci * 36 + k * 4];
          du8[k] = *(const f32x4*)&sDU[ci * 36 + k * 4];
          bt[k]  = *(const f32x4*)&sBT[s * 36 + k * 4];
          ct[k]  = *(const f32x4*)&sCT[s * 36 + k * 4];
        }
#pragma unroll
        for (int t = 0; t < TCH; t++) {
          ee[t] = __expf(dl[t >> 2][t & 3] * Av);
          cin[t] = du8[t >> 2][t & 3] * bt[t >> 2][t & 3];
        }
      }
      float pv0 = 0.f, pv1 = 0.f;
#pragma unroll
      for (int t = 0; t < TCH; t++) {
        h = h * ee[t] + cin[t];
        float p = sum16(h * ct[t >> 2][t & 3]);
        if (t < 16) pv0 = (s == t) ? p : pv0;
        else        pv1 = (s == (t - 16)) ? p : pv1;
      }
      sY[s * 17 + ci] = pv0;
      sY[(s + 16) * 17 + ci] = pv1;
    }
    __syncthreads();   // B2

    {
      float p0 = sY[tt * 17 + j];
      float p1 = sY[(tt + 16) * 17 + j];
      float y0 = p0 + uv0 * Ddj;
      float y1 = p1 + uv1 * Ddj;
      float g0 = zv0 / (1.f + __expf(-zv0));
      float g1 = zv1 / (1.f + __expf(-zv1));
      ybb[(size_t)(t0 + tt) * 512 + j] = f2bf(y0 * g0);
      ybb[(size_t)(t0 + tt + 16) * 512 + j] = f2bf(y1 * g1);
    }
    if (c + 1 < NCH) {
#pragma unroll
      for (int k = 0; k < 6; k++) {
        int r = rr[k], t = tr[k];
        if (r < 16)      sDt[t * 20 + r] = pjn[k];
        else if (r < 32) sBT[(r - 16) * 36 + t] = pjn[k];
        else             sCT[(r - 32) * 36 + t] = pjn[k];
      }
      sUT[j * 36 + tt] = un0;
      sUT[j * 36 + tt + 16] = un1;
      uv0 = un0; uv1 = un1; zv0 = zn0; zv1 = zn1;
    }
    __syncthreads();   // B3
  }
}

// ---------------- final LN + head dot + sigmoid; one WAVE per token (bf16 h) ----------------
__global__ void head_kernel(const short* __restrict__ h, const float* __restrict__ g,
                            const float* __restrict__ bv, const float* __restrict__ hw,
                            const float* __restrict__ hb, float* __restrict__ out) {
  int token = blockIdx.x * 4 + (threadIdx.x >> 6);
  int lane = threadIdx.x & 63;
  short4v xv = *(const short4v*)(h + (size_t)token * DM + lane * 4);
  f32x4 v;
#pragma unroll
  for (int k = 0; k < 4; k++) v[k] = bf2f(xv[k]);
  float s = v[0] + v[1] + v[2] + v[3];
  float q = v[0]*v[0] + v[1]*v[1] + v[2]*v[2] + v[3]*v[3];
#pragma unroll
  for (int off = 32; off > 0; off >>= 1) {
    s += __shfl_xor(s, off, 64);
    q += __shfl_xor(q, off, 64);
  }
  float mu = s * (1.f / DM);
  float rs = rsqrtf(q * (1.f / DM) - mu * mu + 1e-5f);
  f32x4 gg = *(const f32x4*)(g + lane * 4);
  f32x4 bb = *(const f32x4*)(bv + lane * 4);
  f32x4 ww = *(const f32x4*)(hw + lane * 4);
  float c = 0.f;
#pragma unroll
  for (int k = 0; k < 4; k++) c += ((v[k] - mu) * rs * gg[k] + bb[k]) * ww[k];
#pragma unroll
  for (int off = 32; off > 0; off >>= 1) c += __shfl_xor(c, off, 64);
  if (lane == 0) out[token] = 1.f / (1.f + __expf(-(c + hb[0])));
}

extern "C" void kernel_launch(void* const* d_in, const int* in_sizes, int n_in,
                              void* d_out, int out_size, void* d_ws, size_t ws_size,
                              hipStream_t stream) {
  const float* x        = (const float*)d_in[0];
  const float* stem_w   = (const float*)d_in[1];
  const float* stem_b   = (const float*)d_in[2];
  const float* norm_g   = (const float*)d_in[3];
  const float* norm_b   = (const float*)d_in[4];
  const float* in_proj_w= (const float*)d_in[5];
  const float* conv_w   = (const float*)d_in[6];
  const float* conv_b   = (const float*)d_in[7];
  const float* x_proj_w = (const float*)d_in[8];
  const float* dt_w     = (const float*)d_in[9];
  const float* dt_b     = (const float*)d_in[10];
  const float* A_log    = (const float*)d_in[11];
  const float* Dp       = (const float*)d_in[12];
  const float* out_w    = (const float*)d_in[13];
  const float* fnorm_g  = (const float*)d_in[14];
  const float* fnorm_b  = (const float*)d_in[15];
  const float* head_w   = (const float*)d_in[16];
  const float* head_b   = (const float*)d_in[17];

  char* base = (char*)d_ws;
  short* h    = (short*)(base);                           // 8 MB (bf16 residual)
  short* xcb  = (short*)(base + ((size_t)16 << 20));      // 16 MB
  short* zcb  = (short*)(base + ((size_t)32 << 20));      // 16 MB
  short* xnb  = (short*)(base + ((size_t)48 << 20));      // 8 MB
  short* xinb = (short*)(base + ((size_t)56 << 20));      // 16 MB
  short* ybf  = (short*)(base + ((size_t)72 << 20));      // 16 MB
  float* proj = (float*)(base + ((size_t)88 << 20));      // 3 MB
  short* wb   = (short*)(base + ((size_t)91 << 20));      // 3.5 MB

  stem_kernel<<<NT, 256, 0, stream>>>(x, stem_w, stem_b, h);

  dim3 gcw(WB_L / 256, 4);
  convert_w<<<gcw, 256, 0, stream>>>(in_proj_w, x_proj_w, out_w, wb);

  for (int i = 0; i < 4; i++) {
    const short* wbl = wb + (size_t)i * WB_L;

    ln_kernel<<<NT / 4, 256, 0, stream>>>(h, norm_g + i * DM, norm_b + i * DM, xnb);

    dim3 g1(8, NT / 128);
    gemm_mfma_s16<<<g1, 256, 0, stream>>>(xnb, 256, wbl, xcb, 512, zcb, 512, 512, 1024);

    dim3 g2(1, NT / 32);
    gemm2_conv<<<g2, 256, 0, stream>>>(xcb, conv_w + i * DI * 4, conv_b + i * DI,
                                       wbl + WB_IN, xinb, proj);

    scan_kernel<<<512, 256, 0, stream>>>(xinb, proj, zcb,
                                         dt_w + (size_t)i * DI * 16, dt_b + i * DI,
                                         A_log + (size_t)i * DI * 16, Dp + i * DI, ybf);

    dim3 g3(4, NT / 64);
    gemm_mfma64<<<g3, 256, 0, stream>>>(ybf, 512, wbl + WB_IN + WB_XP, h, 256, 256, 1);
  }

  head_kernel<<<NT / 4, 256, 0, stream>>>(h, fnorm_g, fnorm_b, head_w, head_b, (float*)d_out);
}